// Round 3
// baseline (647.657 us; speedup 1.0000x reference)
//
#include <hip/hip_runtime.h>

#define E_      8
#define D_      1024
#define H_      2048
#define TOKENS  8192
#define RROWS   16384            // routed rows total (= TOKENS * TOP_K), exact
#define HPAD_ROWS (RROWS + 256)  // pad so GEMM2 A-staging over-read stays in bounds

using bf16x8 = __attribute__((ext_vector_type(8))) __bf16;
using f32x4  = __attribute__((ext_vector_type(4))) float;

__device__ __forceinline__ unsigned short f2bf(float f) {
  unsigned u = __builtin_bit_cast(unsigned, f);
  u += 0x7fffu + ((u >> 16) & 1u);   // RNE
  return (unsigned short)(u >> 16);
}

// async global->LDS, 16B per lane; LDS dest is wave-uniform base + lane*16
#define GLDS16(g, l) __builtin_amdgcn_global_load_lds( \
    (const __attribute__((address_space(1))) unsigned int*)(g), \
    (__attribute__((address_space(3))) unsigned int*)(l), 16, 0, 0)

#define SBAR() asm volatile("s_barrier" ::: "memory")

// ---------------- prologue kernels ----------------

// src: [E][R][C] fp32  ->  dst: [E][C][R] bf16
__global__ void transpose_cvt_kernel(const float* __restrict__ src,
                                     unsigned short* __restrict__ dst,
                                     int R, int C) {
  int tilesC = C >> 6, tilesR = R >> 6;
  int per = tilesR * tilesC;
  int b = blockIdx.x;
  int e = b / per, rem = b % per;
  int rb = rem / tilesC, cb = rem % tilesC;
  __shared__ float tile[64][65];
  const float* s = src + (size_t)e * R * C;
  unsigned short* d = dst + (size_t)e * R * C;
  int r0 = rb << 6, c0 = cb << 6;
#pragma unroll
  for (int i = 0; i < 16; i++) {
    int idx = threadIdx.x + i * 256;
    int lr = idx >> 6, lc = idx & 63;
    tile[lr][lc] = s[(size_t)(r0 + lr) * C + (c0 + lc)];
  }
  __syncthreads();
#pragma unroll
  for (int i = 0; i < 16; i++) {
    int idx = threadIdx.x + i * 256;
    int lr = idx >> 6, lc = idx & 63;
    d[(size_t)(c0 + lr) * R + (r0 + lc)] = f2bf(tile[lc][lr]);
  }
}

// gating + x -> bf16 conversion fused (both consume the full x read)
__global__ void gating_kernel(const float* __restrict__ x, const float* __restrict__ gate,
                              unsigned short* __restrict__ xb,
                              int* __restrict__ sel, float* __restrict__ wsel,
                              int* __restrict__ cnt) {
  int lane = threadIdx.x & 63, wid = threadIdx.x >> 6;
  int t = (blockIdx.x << 2) + wid;          // one wave per token
  const float* xr = x + (size_t)t * D_;
  unsigned short* xbr = xb + (size_t)t * D_;
  float acc[8];
#pragma unroll
  for (int e = 0; e < 8; e++) acc[e] = 0.f;
  for (int i = 0; i < D_ / 64; i++) {
    int dd = (i << 6) + lane;
    float xv = xr[dd];
    xbr[dd] = f2bf(xv);
    const float4* g4 = reinterpret_cast<const float4*>(gate + dd * 8);
    float4 ga = g4[0], gb = g4[1];
    acc[0] += xv * ga.x; acc[1] += xv * ga.y; acc[2] += xv * ga.z; acc[3] += xv * ga.w;
    acc[4] += xv * gb.x; acc[5] += xv * gb.y; acc[6] += xv * gb.z; acc[7] += xv * gb.w;
  }
#pragma unroll
  for (int e = 0; e < 8; e++) {
#pragma unroll
    for (int off = 32; off; off >>= 1) acc[e] += __shfl_xor(acc[e], off);
  }
  if (lane == 0) {
    int i0 = 0; float v0 = acc[0];
#pragma unroll
    for (int e = 1; e < 8; e++) if (acc[e] > v0) { v0 = acc[e]; i0 = e; }
    int i1 = -1; float v1 = -3.4e38f;
#pragma unroll
    for (int e = 0; e < 8; e++) if (e != i0 && acc[e] > v1) { v1 = acc[e]; i1 = e; }
    float p1 = expf(v1 - v0);
    float inv = 1.f / (1.f + p1);
    sel[t * 2] = i0; sel[t * 2 + 1] = i1;
    wsel[t * 2] = inv; wsel[t * 2 + 1] = p1 * inv;
    atomicAdd(&cnt[i0], 1);
    atomicAdd(&cnt[i1], 1);
  }
}

__global__ void scan_kernel(const int* __restrict__ cnt, int* __restrict__ off,
                            int* __restrict__ cursor) {
  if (threadIdx.x == 0) {
    int a = 0;
    for (int e = 0; e < 8; e++) { off[e] = a; cursor[e] = a; a += cnt[e]; }
  }
}

__global__ void scatter_kernel(const int* __restrict__ sel, const float* __restrict__ wsel,
                               int* __restrict__ cursor, int* __restrict__ tok_id,
                               float* __restrict__ rw) {
  int t = blockIdx.x * blockDim.x + threadIdx.x;
  if (t >= TOKENS) return;
  int e0 = sel[t * 2], e1 = sel[t * 2 + 1];
  int p0 = atomicAdd(&cursor[e0], 1);
  tok_id[p0] = t; rw[p0] = wsel[t * 2];
  int p1 = atomicAdd(&cursor[e1], 1);
  tok_id[p1] = t; rw[p1] = wsel[t * 2 + 1];
}

// ---------------- grouped GEMMs: 256x256 tile, 8-phase counted-vmcnt ----------------
// 8 waves (2M x 4N), per-wave output 128x64, acc[8][4] f32x4.
// LDS: 4-slot ring of K-half tiles (256 rows x 32 k x 2B = 16KB) per operand,
// 4*16KB*2 = 128KB. Slot for K-half kh = kh&3. Per kh: 2 phases (m0-3, m4-7),
// 16 MFMA each; phase A stages A-half(kh+3), phase B stages B-half(kh+3);
// vmcnt(8) once per kh (counted: 2 newer K-halves stay in flight). Swizzle:
// 64B rows, 16B chunk ^= (row&3)^((row>>2)&3), applied on the GLOBAL source
// (LDS stays linear) and on the ds_read chunk index -> 2-way (free) banks.

__global__ __launch_bounds__(512, 1) void gemm1_kernel(
    const unsigned short* __restrict__ xb,    // [TOKENS][D_] bf16
    const unsigned short* __restrict__ w1t,   // [E][H][D] bf16 (k=d contiguous)
    const float* __restrict__ b1,             // [E][H]
    unsigned short* __restrict__ hbuf,        // [HPAD_ROWS][H_] bf16
    const int* __restrict__ tok_id,
    const int* __restrict__ cnt, const int* __restrict__ off) {
  const int nwg = E_ * 32 * 8;               // 2048
  const int raw = blockIdx.x;
  const int bid = (raw & 7) * (nwg >> 3) + (raw >> 3);   // expert e -> XCD e
  const int e  = bid >> 8;
  const int rb = (bid >> 3) & 31;
  const int cb = bid & 7;
  const int rows = cnt[e];
  const int m0 = rb << 8;
  if (m0 >= rows) return;
  const int base = off[e];
  const int tid = threadIdx.x, lane = tid & 63, wid = tid >> 6;
  const int wr = wid >> 2, wc = wid & 3;

  __shared__ __align__(16) unsigned short Asm[4][256 * 32];
  __shared__ __align__(16) unsigned short Bsm[4][256 * 32];

  // per-thread staging constants: issue i covers row i*128 + wid*16 + (lane>>2),
  // nominal chunk lane&3, global chunk ^= swz(row) = ((lane>>2)&3)^((lane>>4)&3)
  const int swzc = (lane & 3) ^ ((lane >> 2) & 3) ^ ((lane >> 4) & 3);
  const int srow0 = wid * 16 + (lane >> 2);
  const int srow1 = 128 + srow0;
  const int n0 = cb << 8;
  int ar0 = m0 + srow0; if (ar0 >= rows) ar0 = rows - 1;
  int ar1 = m0 + srow1; if (ar1 >= rows) ar1 = rows - 1;
  const int tok0 = tok_id[base + ar0];
  const int tok1 = tok_id[base + ar1];
  const char* Ab = (const char*)xb;
  const char* Bb = (const char*)w1t + (size_t)e * H_ * D_ * 2;
  const size_t aOff0 = (size_t)tok0 * (D_ * 2) + (size_t)(swzc << 4);
  const size_t aOff1 = (size_t)tok1 * (D_ * 2) + (size_t)(swzc << 4);
  const size_t bOff0 = (size_t)(n0 + srow0) * (D_ * 2) + (size_t)(swzc << 4);
  const size_t bOff1 = (size_t)(n0 + srow1) * (D_ * 2) + (size_t)(swzc << 4);
  const int ldsOff = wid << 10;              // wid*1024 (wave-uniform)

  // frag-read constants: row = (wr*128|wc*64) + m*16 + (lane&15), chunk = (lane>>4)^swz(row)
  const int arow_rd = ((wr << 7) + (lane & 15)) * 64 + (((lane >> 4) ^ ((lane & 3) ^ ((lane >> 2) & 3))) << 4);
  const int brow_rd = ((wc << 6) + (lane & 15)) * 64 + (((lane >> 4) ^ ((lane & 3) ^ ((lane >> 2) & 3))) << 4);

  f32x4 acc[8][4] = {};
  const int KH = D_ / 32;   // 32

  // prologue: stage K-halves 0,1,2 (12 loads/thread outstanding)
#pragma unroll
  for (int kh = 0; kh < 3; ++kh) {
    const size_t ko = (size_t)kh << 6;
    GLDS16(Ab + aOff0 + ko, (unsigned short*)((char*)&Asm[kh][0] + ldsOff));
    GLDS16(Ab + aOff1 + ko, (unsigned short*)((char*)&Asm[kh][0] + 8192 + ldsOff));
    GLDS16(Bb + bOff0 + ko, (unsigned short*)((char*)&Bsm[kh][0] + ldsOff));
    GLDS16(Bb + bOff1 + ko, (unsigned short*)((char*)&Bsm[kh][0] + 8192 + ldsOff));
  }
  asm volatile("s_waitcnt vmcnt(8)" ::: "memory");   // K-half 0 landed
  SBAR();

  for (int kh = 0; kh < KH; ++kh) {
    const int slot = kh & 3;
    const char* Arow = (const char*)&Asm[slot][0] + arow_rd;
    const char* Brow = (const char*)&Bsm[slot][0] + brow_rd;
    bf16x8 a[4], b[4];
    // ---- phase A: B n0-3 + A m0-3; stage A-half(kh+3) ----
#pragma unroll
    for (int n = 0; n < 4; n++) b[n] = *(const bf16x8*)(Brow + (n << 10));
#pragma unroll
    for (int m = 0; m < 4; m++) a[m] = *(const bf16x8*)(Arow + (m << 10));
    if (kh + 3 < KH) {
      const int s3 = (kh + 3) & 3;
      const size_t ko = (size_t)(kh + 3) << 6;
      GLDS16(Ab + aOff0 + ko, (unsigned short*)((char*)&Asm[s3][0] + ldsOff));
      GLDS16(Ab + aOff1 + ko, (unsigned short*)((char*)&Asm[s3][0] + 8192 + ldsOff));
    }
    SBAR();
    __builtin_amdgcn_s_setprio(1);
#pragma unroll
    for (int m = 0; m < 4; m++)
#pragma unroll
      for (int n = 0; n < 4; n++)
        acc[m][n] = __builtin_amdgcn_mfma_f32_16x16x32_bf16(a[m], b[n], acc[m][n], 0, 0, 0);
    __builtin_amdgcn_s_setprio(0);
    SBAR();
    // ---- phase B: A m4-7 (reuse b); stage B-half(kh+3); counted vmcnt ----
#pragma unroll
    for (int m = 0; m < 4; m++) a[m] = *(const bf16x8*)(Arow + ((m + 4) << 10));
    if (kh + 3 < KH) {
      const int s3 = (kh + 3) & 3;
      const size_t ko = (size_t)(kh + 3) << 6;
      GLDS16(Bb + bOff0 + ko, (unsigned short*)((char*)&Bsm[s3][0] + ldsOff));
      GLDS16(Bb + bOff1 + ko, (unsigned short*)((char*)&Bsm[s3][0] + 8192 + ldsOff));
      asm volatile("s_waitcnt vmcnt(8)" ::: "memory");     // kh+1 landed, kh+2/kh+3 in flight
    } else if (kh + 2 < KH) {
      asm volatile("s_waitcnt vmcnt(4)" ::: "memory");
    } else if (kh + 1 < KH) {
      asm volatile("s_waitcnt vmcnt(0)" ::: "memory");
    }
    SBAR();
    __builtin_amdgcn_s_setprio(1);
#pragma unroll
    for (int m = 0; m < 4; m++)
#pragma unroll
      for (int n = 0; n < 4; n++)
        acc[m + 4][n] = __builtin_amdgcn_mfma_f32_16x16x32_bf16(a[m], b[n], acc[m + 4][n], 0, 0, 0);
    __builtin_amdgcn_s_setprio(0);
    SBAR();
  }

  const int rcnt = rows - m0;
  const float* b1e = b1 + e * H_;
#pragma unroll
  for (int m = 0; m < 8; m++) {
#pragma unroll
    for (int q = 0; q < 4; q++) {
      int rl = (wr << 7) + (m << 4) + ((lane >> 4) << 2) + q;
      if (rl < rcnt) {
        unsigned short* hrow = hbuf + (size_t)(base + m0 + rl) * H_;
#pragma unroll
        for (int n = 0; n < 4; n++) {
          int ncol = n0 + (wc << 6) + (n << 4) + (lane & 15);
          float v = acc[m][n][q] + b1e[ncol];
          hrow[ncol] = f2bf(fmaxf(v, 0.f));
        }
      }
    }
  }
}

__global__ __launch_bounds__(512, 1) void gemm2_kernel(
    const unsigned short* __restrict__ hbuf,  // [HPAD_ROWS][H_] bf16
    const unsigned short* __restrict__ w2t,   // [E][D][H] bf16 (k=h contiguous)
    const float* __restrict__ b2,             // [E][D]
    float* __restrict__ out,                  // [TOKENS][D_] fp32 (zeroed)
    const int* __restrict__ tok_id, const float* __restrict__ rw,
    const int* __restrict__ cnt, const int* __restrict__ off) {
  const int nwg = E_ * 32 * 4;               // 1024
  const int raw = blockIdx.x;
  const int bid = (raw & 7) * (nwg >> 3) + (raw >> 3);   // expert e -> XCD e
  const int e  = bid >> 7;
  const int rb = (bid >> 2) & 31;
  const int cb = bid & 3;
  const int rows = cnt[e];
  const int m0 = rb << 8;
  if (m0 >= rows) return;
  const int base = off[e];
  const int tid = threadIdx.x, lane = tid & 63, wid = tid >> 6;
  const int wr = wid >> 2, wc = wid & 3;

  __shared__ __align__(16) unsigned short Asm[4][256 * 32];
  __shared__ __align__(16) unsigned short Bsm[4][256 * 32];

  const int swzc = (lane & 3) ^ ((lane >> 2) & 3) ^ ((lane >> 4) & 3);
  const int srow0 = wid * 16 + (lane >> 2);
  const int srow1 = 128 + srow0;
  const int n0 = cb << 8;
  const char* Ab = (const char*)hbuf;
  const char* Bb = (const char*)w2t + (size_t)e * D_ * H_ * 2;
  const size_t aOff0 = (size_t)(base + m0 + srow0) * (H_ * 2) + (size_t)(swzc << 4);
  const size_t aOff1 = (size_t)(base + m0 + srow1) * (H_ * 2) + (size_t)(swzc << 4);
  const size_t bOff0 = (size_t)(n0 + srow0) * (H_ * 2) + (size_t)(swzc << 4);
  const size_t bOff1 = (size_t)(n0 + srow1) * (H_ * 2) + (size_t)(swzc << 4);
  const int ldsOff = wid << 10;

  const int arow_rd = ((wr << 7) + (lane & 15)) * 64 + (((lane >> 4) ^ ((lane & 3) ^ ((lane >> 2) & 3))) << 4);
  const int brow_rd = ((wc << 6) + (lane & 15)) * 64 + (((lane >> 4) ^ ((lane & 3) ^ ((lane >> 2) & 3))) << 4);

  f32x4 acc[8][4] = {};
  const int KH = H_ / 32;   // 64

#pragma unroll
  for (int kh = 0; kh < 3; ++kh) {
    const size_t ko = (size_t)kh << 6;
    GLDS16(Ab + aOff0 + ko, (unsigned short*)((char*)&Asm[kh][0] + ldsOff));
    GLDS16(Ab + aOff1 + ko, (unsigned short*)((char*)&Asm[kh][0] + 8192 + ldsOff));
    GLDS16(Bb + bOff0 + ko, (unsigned short*)((char*)&Bsm[kh][0] + ldsOff));
    GLDS16(Bb + bOff1 + ko, (unsigned short*)((char*)&Bsm[kh][0] + 8192 + ldsOff));
  }
  asm volatile("s_waitcnt vmcnt(8)" ::: "memory");
  SBAR();

  for (int kh = 0; kh < KH; ++kh) {
    const int slot = kh & 3;
    const char* Arow = (const char*)&Asm[slot][0] + arow_rd;
    const char* Brow = (const char*)&Bsm[slot][0] + brow_rd;
    bf16x8 a[4], b[4];
#pragma unroll
    for (int n = 0; n < 4; n++) b[n] = *(const bf16x8*)(Brow + (n << 10));
#pragma unroll
    for (int m = 0; m < 4; m++) a[m] = *(const bf16x8*)(Arow + (m << 10));
    if (kh + 3 < KH) {
      const int s3 = (kh + 3) & 3;
      const size_t ko = (size_t)(kh + 3) << 6;
      GLDS16(Ab + aOff0 + ko, (unsigned short*)((char*)&Asm[s3][0] + ldsOff));
      GLDS16(Ab + aOff1 + ko, (unsigned short*)((char*)&Asm[s3][0] + 8192 + ldsOff));
    }
    SBAR();
    __builtin_amdgcn_s_setprio(1);
#pragma unroll
    for (int m = 0; m < 4; m++)
#pragma unroll
      for (int n = 0; n < 4; n++)
        acc[m][n] = __builtin_amdgcn_mfma_f32_16x16x32_bf16(a[m], b[n], acc[m][n], 0, 0, 0);
    __builtin_amdgcn_s_setprio(0);
    SBAR();
#pragma unroll
    for (int m = 0; m < 4; m++) a[m] = *(const bf16x8*)(Arow + ((m + 4) << 10));
    if (kh + 3 < KH) {
      const int s3 = (kh + 3) & 3;
      const size_t ko = (size_t)(kh + 3) << 6;
      GLDS16(Bb + bOff0 + ko, (unsigned short*)((char*)&Bsm[s3][0] + ldsOff));
      GLDS16(Bb + bOff1 + ko, (unsigned short*)((char*)&Bsm[s3][0] + 8192 + ldsOff));
      asm volatile("s_waitcnt vmcnt(8)" ::: "memory");
    } else if (kh + 2 < KH) {
      asm volatile("s_waitcnt vmcnt(4)" ::: "memory");
    } else if (kh + 1 < KH) {
      asm volatile("s_waitcnt vmcnt(0)" ::: "memory");
    }
    SBAR();
    __builtin_amdgcn_s_setprio(1);
#pragma unroll
    for (int m = 0; m < 4; m++)
#pragma unroll
      for (int n = 0; n < 4; n++)
        acc[m + 4][n] = __builtin_amdgcn_mfma_f32_16x16x32_bf16(a[m], b[n], acc[m + 4][n], 0, 0, 0);
    __builtin_amdgcn_s_setprio(0);
    SBAR();
  }

  const int rcnt = rows - m0;
  const float* b2e = b2 + e * D_;
#pragma unroll
  for (int m = 0; m < 8; m++) {
#pragma unroll
    for (int q = 0; q < 4; q++) {
      int rl = (wr << 7) + (m << 4) + ((lane >> 4) << 2) + q;
      if (rl < rcnt) {
        int R = base + m0 + rl;
        float w = rw[R];
        int t = tok_id[R];
        float* orow = out + (size_t)t * D_;
#pragma unroll
        for (int n = 0; n < 4; n++) {
          int ncol = n0 + (wc << 6) + (n << 4) + (lane & 15);
          atomicAdd(&orow[ncol], w * (acc[m][n][q] + b2e[ncol]));
        }
      }
    }
  }
}

// ---------------- launcher ----------------

extern "C" void kernel_launch(void* const* d_in, const int* in_sizes, int n_in,
                              void* d_out, int out_size, void* d_ws, size_t ws_size,
                              hipStream_t stream) {
  (void)in_sizes; (void)n_in; (void)ws_size;
  const float* x    = (const float*)d_in[0];
  const float* gate = (const float*)d_in[1];
  const float* W1   = (const float*)d_in[2];
  const float* b1   = (const float*)d_in[3];
  const float* W2   = (const float*)d_in[4];
  const float* b2   = (const float*)d_in[5];
  float* out = (float*)d_out;

  char* p = (char*)d_ws;
  unsigned short* xb   = (unsigned short*)p; p += (size_t)TOKENS * D_ * 2;
  unsigned short* w1t  = (unsigned short*)p; p += (size_t)E_ * H_ * D_ * 2;
  unsigned short* w2t  = (unsigned short*)p; p += (size_t)E_ * D_ * H_ * 2;
  unsigned short* hbuf = (unsigned short*)p; p += (size_t)HPAD_ROWS * H_ * 2;
  int*   tok  = (int*)p;   p += (size_t)RROWS * 4;
  float* rw   = (float*)p; p += (size_t)RROWS * 4;
  int*   sel  = (int*)p;   p += (size_t)TOKENS * 2 * 4;
  float* wsel = (float*)p; p += (size_t)TOKENS * 2 * 4;
  int* cnt    = (int*)p;   p += 32 * 4;
  int* off    = (int*)p;   p += 32 * 4;
  int* cursor = (int*)p;   p += 32 * 4;

  hipMemsetAsync(cnt, 0, 32 * 4, stream);
  hipMemsetAsync(out, 0, (size_t)out_size * 4, stream);

  transpose_cvt_kernel<<<E_ * (D_ / 64) * (H_ / 64), 256, 0, stream>>>(W1, w1t, D_, H_);
  transpose_cvt_kernel<<<E_ * (H_ / 64) * (D_ / 64), 256, 0, stream>>>(W2, w2t, H_, D_);
  gating_kernel<<<TOKENS / 4, 256, 0, stream>>>(x, gate, xb, sel, wsel, cnt);
  scan_kernel<<<1, 64, 0, stream>>>(cnt, off, cursor);
  scatter_kernel<<<TOKENS / 256, 256, 0, stream>>>(sel, wsel, cursor, tok, rw);
  gemm1_kernel<<<E_ * 32 * 8, 512, 0, stream>>>(xb, w1t, b1, hbuf, tok, cnt, off);
  gemm2_kernel<<<E_ * 32 * 4, 512, 0, stream>>>(hbuf, w2t, b2, out, tok, rw, cnt, off);
}

// Round 4
// 575.900 us; speedup vs baseline: 1.1246x; 1.1246x over previous
//
#include <hip/hip_runtime.h>

#define E_      8
#define D_      1024
#define H_      2048
#define TOKENS  8192
#define RROWS   16384            // routed rows total (= TOKENS * TOP_K), exact
#define HPAD_ROWS (RROWS + 128)  // pad so GEMM2 A-staging over-read stays in bounds

using bf16x8 = __attribute__((ext_vector_type(8))) __bf16;
using f32x4  = __attribute__((ext_vector_type(4))) float;

__device__ __forceinline__ unsigned short f2bf(float f) {
  unsigned u = __builtin_bit_cast(unsigned, f);
  u += 0x7fffu + ((u >> 16) & 1u);   // RNE
  return (unsigned short)(u >> 16);
}
__device__ __forceinline__ float bf2f(unsigned short u) {
  unsigned v = (unsigned)u << 16;
  return __builtin_bit_cast(float, v);
}

// async global->LDS, 16B per lane; LDS dest is wave-uniform base + lane*16
#define GLDS16(g, l) __builtin_amdgcn_global_load_lds( \
    (const __attribute__((address_space(1))) unsigned int*)(g), \
    (__attribute__((address_space(3))) unsigned int*)(l), 16, 0, 0)

#define SBAR() asm volatile("s_barrier" ::: "memory")

// ---------------- prologue kernels ----------------

// src: [E][R][C] fp32  ->  dst: [E][C][R] bf16
__global__ void transpose_cvt_kernel(const float* __restrict__ src,
                                     unsigned short* __restrict__ dst,
                                     int R, int C) {
  int tilesC = C >> 6, tilesR = R >> 6;
  int per = tilesR * tilesC;
  int b = blockIdx.x;
  int e = b / per, rem = b % per;
  int rb = rem / tilesC, cb = rem % tilesC;
  __shared__ float tile[64][65];
  const float* s = src + (size_t)e * R * C;
  unsigned short* d = dst + (size_t)e * R * C;
  int r0 = rb << 6, c0 = cb << 6;
#pragma unroll
  for (int i = 0; i < 16; i++) {
    int idx = threadIdx.x + i * 256;
    int lr = idx >> 6, lc = idx & 63;
    tile[lr][lc] = s[(size_t)(r0 + lr) * C + (c0 + lc)];
  }
  __syncthreads();
#pragma unroll
  for (int i = 0; i < 16; i++) {
    int idx = threadIdx.x + i * 256;
    int lr = idx >> 6, lc = idx & 63;
    d[(size_t)(c0 + lr) * R + (r0 + lc)] = f2bf(tile[lc][lr]);
  }
}

// gating + x -> bf16 conversion fused (both consume the full x read)
__global__ void gating_kernel(const float* __restrict__ x, const float* __restrict__ gate,
                              unsigned short* __restrict__ xb,
                              int* __restrict__ sel, float* __restrict__ wsel,
                              int* __restrict__ cnt) {
  int lane = threadIdx.x & 63, wid = threadIdx.x >> 6;
  int t = (blockIdx.x << 2) + wid;          // one wave per token
  const float* xr = x + (size_t)t * D_;
  unsigned short* xbr = xb + (size_t)t * D_;
  float acc[8];
#pragma unroll
  for (int e = 0; e < 8; e++) acc[e] = 0.f;
  for (int i = 0; i < D_ / 64; i++) {
    int dd = (i << 6) + lane;
    float xv = xr[dd];
    xbr[dd] = f2bf(xv);
    const float4* g4 = reinterpret_cast<const float4*>(gate + dd * 8);
    float4 ga = g4[0], gb = g4[1];
    acc[0] += xv * ga.x; acc[1] += xv * ga.y; acc[2] += xv * ga.z; acc[3] += xv * ga.w;
    acc[4] += xv * gb.x; acc[5] += xv * gb.y; acc[6] += xv * gb.z; acc[7] += xv * gb.w;
  }
#pragma unroll
  for (int e = 0; e < 8; e++) {
#pragma unroll
    for (int off = 32; off; off >>= 1) acc[e] += __shfl_xor(acc[e], off);
  }
  if (lane == 0) {
    int i0 = 0; float v0 = acc[0];
#pragma unroll
    for (int e = 1; e < 8; e++) if (acc[e] > v0) { v0 = acc[e]; i0 = e; }
    int i1 = -1; float v1 = -3.4e38f;
#pragma unroll
    for (int e = 0; e < 8; e++) if (e != i0 && acc[e] > v1) { v1 = acc[e]; i1 = e; }
    float p1 = expf(v1 - v0);
    float inv = 1.f / (1.f + p1);
    sel[t * 2] = i0; sel[t * 2 + 1] = i1;
    wsel[t * 2] = inv; wsel[t * 2 + 1] = p1 * inv;
    atomicAdd(&cnt[i0], 1);
    atomicAdd(&cnt[i1], 1);
  }
}

__global__ void scan_kernel(const int* __restrict__ cnt, int* __restrict__ off,
                            int* __restrict__ cursor) {
  if (threadIdx.x == 0) {
    int a = 0;
    for (int e = 0; e < 8; e++) { off[e] = a; cursor[e] = a; a += cnt[e]; }
  }
}

__global__ void scatter_kernel(const int* __restrict__ sel,
                               int* __restrict__ cursor, int* __restrict__ tok_id,
                               int* __restrict__ pos) {
  int t = blockIdx.x * blockDim.x + threadIdx.x;
  if (t >= TOKENS) return;
  int e0 = sel[t * 2], e1 = sel[t * 2 + 1];
  int p0 = atomicAdd(&cursor[e0], 1);
  tok_id[p0] = t; pos[t * 2] = p0;
  int p1 = atomicAdd(&cursor[e1], 1);
  tok_id[p1] = t; pos[t * 2 + 1] = p1;
}

// ---------------- grouped GEMMs ----------------
// 128x128 tile, 4 waves (2x2), 16x16x32 bf16 MFMA, 2 blocks/CU (64KB LDS).
// LDS: 4-slot ring of BK=32 K-halves per operand (128 rows x 32 k x 2B = 8KB
// per slot). Counted-vmcnt pipeline (T4): slot kh+3 staged at iter kh,
// vmcnt(8) per iter (2 K-halves stay in flight across raw s_barrier).
// Swizzle: 64B rows, 16B chunk ^= (row&3)^((row>>2)&3), folded into the
// per-lane GLOBAL source address (LDS dest linear) and the ds_read chunk.
// XCD-chunked swizzle: expert e's blocks all land on XCD e (B panel L2-hot).

__global__ __launch_bounds__(256) void gemm1_kernel(
    const unsigned short* __restrict__ xb,    // [TOKENS][D_] bf16
    const unsigned short* __restrict__ w1t,   // [E][H][D] bf16 (k=d contiguous)
    const float* __restrict__ b1,             // [E][H]
    unsigned short* __restrict__ hbuf,        // [HPAD_ROWS][H_] bf16
    const int* __restrict__ tok_id,
    const int* __restrict__ cnt, const int* __restrict__ off) {
  const int nwg = E_ * 64 * 16;
  const int raw = blockIdx.x;
  const int bid = (raw & 7) * (nwg >> 3) + (raw >> 3);
  const int e  = bid >> 10;
  const int rb = (bid >> 4) & 63;
  const int cb = bid & 15;
  const int rows = cnt[e];
  const int m0 = rb << 7;
  if (m0 >= rows) return;
  const int base = off[e];
  const int tid = threadIdx.x, lane = tid & 63, wid = tid >> 6;
  const int wr = wid >> 1, wc = wid & 1;

  __shared__ __align__(16) unsigned short Asm[4][128 * 32];
  __shared__ __align__(16) unsigned short Bsm[4][128 * 32];

  // staging: wave wid, issue i covers rows (wid+i*4)*16 .. +15
  const int swzc = ((lane >> 2) & 3) ^ (lane >> 4);        // swz(staged row)
  const size_t chk = (size_t)(((lane & 3) ^ swzc) << 4);   // source chunk byte
  const int r0 = wid * 16 + (lane >> 2);                   // 0..63
  const int r1 = r0 + 64;                                  // 64..127
  const int n0 = cb << 7;
  int ar0 = m0 + r0; if (ar0 >= rows) ar0 = rows - 1;      // clamp (never stored)
  int ar1 = m0 + r1; if (ar1 >= rows) ar1 = rows - 1;
  const char* Ab = (const char*)xb;
  const char* Bb = (const char*)w1t + (size_t)e * H_ * D_ * 2;
  const size_t aO0 = (size_t)tok_id[base + ar0] * (D_ * 2) + chk;
  const size_t aO1 = (size_t)tok_id[base + ar1] * (D_ * 2) + chk;
  const size_t bO0 = (size_t)(n0 + r0) * (D_ * 2) + chk;
  const size_t bO1 = (size_t)(n0 + r1) * (D_ * 2) + chk;
  const int ls0 = wid << 10, ls1 = (wid + 4) << 10;        // wave-uniform LDS bases

  // fragment read: row = w*64 + m*16 + (lane&15), chunk = (lane>>4)^swz(row)
  const int rchunk = (lane >> 4) ^ (lane & 3) ^ ((lane >> 2) & 3);
  const int aRd = ((wr << 6) + (lane & 15)) * 64 + (rchunk << 4);
  const int bRd = ((wc << 6) + (lane & 15)) * 64 + (rchunk << 4);

  f32x4 acc[4][4] = {};
  const int KH = D_ / 32;   // 32

#pragma unroll
  for (int kh = 0; kh < 3; ++kh) {
    const size_t ko = (size_t)kh << 6;
    GLDS16(Ab + aO0 + ko, (unsigned short*)((char*)&Asm[kh][0] + ls0));
    GLDS16(Ab + aO1 + ko, (unsigned short*)((char*)&Asm[kh][0] + ls1));
    GLDS16(Bb + bO0 + ko, (unsigned short*)((char*)&Bsm[kh][0] + ls0));
    GLDS16(Bb + bO1 + ko, (unsigned short*)((char*)&Bsm[kh][0] + ls1));
  }
  asm volatile("s_waitcnt vmcnt(8)" ::: "memory");   // K-half 0 landed
  SBAR();

#pragma unroll 4
  for (int kh = 0; kh < KH; ++kh) {
    const int slot = kh & 3;
    if (kh + 3 < KH) {
      const int s3 = (kh + 3) & 3;
      const size_t ko = (size_t)(kh + 3) << 6;
      GLDS16(Ab + aO0 + ko, (unsigned short*)((char*)&Asm[s3][0] + ls0));
      GLDS16(Ab + aO1 + ko, (unsigned short*)((char*)&Asm[s3][0] + ls1));
      GLDS16(Bb + bO0 + ko, (unsigned short*)((char*)&Bsm[s3][0] + ls0));
      GLDS16(Bb + bO1 + ko, (unsigned short*)((char*)&Bsm[s3][0] + ls1));
    }
    const char* Ap = (const char*)&Asm[slot][0] + aRd;
    const char* Bp = (const char*)&Bsm[slot][0] + bRd;
    bf16x8 a[4], b[4];
#pragma unroll
    for (int m = 0; m < 4; m++) a[m] = *(const bf16x8*)(Ap + (m << 10));
#pragma unroll
    for (int n = 0; n < 4; n++) b[n] = *(const bf16x8*)(Bp + (n << 10));
    __builtin_amdgcn_s_setprio(1);
#pragma unroll
    for (int m = 0; m < 4; m++)
#pragma unroll
      for (int n = 0; n < 4; n++)
        acc[m][n] = __builtin_amdgcn_mfma_f32_16x16x32_bf16(a[m], b[n], acc[m][n], 0, 0, 0);
    __builtin_amdgcn_s_setprio(0);
    if (kh + 3 < KH) {
      asm volatile("s_waitcnt vmcnt(8)" ::: "memory");   // kh+1 landed
    } else if (kh + 2 < KH) {
      asm volatile("s_waitcnt vmcnt(4)" ::: "memory");
    } else if (kh + 1 < KH) {
      asm volatile("s_waitcnt vmcnt(0)" ::: "memory");
    }
    SBAR();
  }

  const int rcnt = rows - m0;
  const float* b1e = b1 + e * H_;
#pragma unroll
  for (int m = 0; m < 4; m++) {
#pragma unroll
    for (int q = 0; q < 4; q++) {
      int rl = (wr << 6) + (m << 4) + ((lane >> 4) << 2) + q;
      if (rl < rcnt) {
        unsigned short* hrow = hbuf + (size_t)(base + m0 + rl) * H_;
#pragma unroll
        for (int n = 0; n < 4; n++) {
          int ncol = n0 + (wc << 6) + (n << 4) + (lane & 15);
          float v = acc[m][n][q] + b1e[ncol];
          hrow[ncol] = f2bf(fmaxf(v, 0.f));
        }
      }
    }
  }
}

__global__ __launch_bounds__(256) void gemm2_kernel(
    const unsigned short* __restrict__ hbuf,  // [HPAD_ROWS][H_] bf16
    const unsigned short* __restrict__ w2t,   // [E][D][H] bf16 (k=h contiguous)
    unsigned short* __restrict__ eout,        // [RROWS][D_] bf16 (per-slot y)
    const int* __restrict__ cnt, const int* __restrict__ off) {
  const int nwg = E_ * 64 * 8;
  const int raw = blockIdx.x;
  const int bid = (raw & 7) * (nwg >> 3) + (raw >> 3);
  const int e  = bid >> 9;
  const int rb = (bid >> 3) & 63;
  const int cb = bid & 7;
  const int rows = cnt[e];
  const int m0 = rb << 7;
  if (m0 >= rows) return;
  const int base = off[e];
  const int tid = threadIdx.x, lane = tid & 63, wid = tid >> 6;
  const int wr = wid >> 1, wc = wid & 1;

  __shared__ __align__(16) unsigned short Asm[4][128 * 32];
  __shared__ __align__(16) unsigned short Bsm[4][128 * 32];

  const int swzc = ((lane >> 2) & 3) ^ (lane >> 4);
  const size_t chk = (size_t)(((lane & 3) ^ swzc) << 4);
  const int r0 = wid * 16 + (lane >> 2);
  const int r1 = r0 + 64;
  const int n0 = cb << 7;
  const char* Ab = (const char*)hbuf;
  const char* Bb = (const char*)w2t + (size_t)e * D_ * H_ * 2;
  const size_t aO0 = (size_t)(base + m0 + r0) * (H_ * 2) + chk;  // pad-safe overread
  const size_t aO1 = (size_t)(base + m0 + r1) * (H_ * 2) + chk;
  const size_t bO0 = (size_t)(n0 + r0) * (H_ * 2) + chk;
  const size_t bO1 = (size_t)(n0 + r1) * (H_ * 2) + chk;
  const int ls0 = wid << 10, ls1 = (wid + 4) << 10;

  const int rchunk = (lane >> 4) ^ (lane & 3) ^ ((lane >> 2) & 3);
  const int aRd = ((wr << 6) + (lane & 15)) * 64 + (rchunk << 4);
  const int bRd = ((wc << 6) + (lane & 15)) * 64 + (rchunk << 4);

  f32x4 acc[4][4] = {};
  const int KH = H_ / 32;   // 64

#pragma unroll
  for (int kh = 0; kh < 3; ++kh) {
    const size_t ko = (size_t)kh << 6;
    GLDS16(Ab + aO0 + ko, (unsigned short*)((char*)&Asm[kh][0] + ls0));
    GLDS16(Ab + aO1 + ko, (unsigned short*)((char*)&Asm[kh][0] + ls1));
    GLDS16(Bb + bO0 + ko, (unsigned short*)((char*)&Bsm[kh][0] + ls0));
    GLDS16(Bb + bO1 + ko, (unsigned short*)((char*)&Bsm[kh][0] + ls1));
  }
  asm volatile("s_waitcnt vmcnt(8)" ::: "memory");
  SBAR();

#pragma unroll 4
  for (int kh = 0; kh < KH; ++kh) {
    const int slot = kh & 3;
    if (kh + 3 < KH) {
      const int s3 = (kh + 3) & 3;
      const size_t ko = (size_t)(kh + 3) << 6;
      GLDS16(Ab + aO0 + ko, (unsigned short*)((char*)&Asm[s3][0] + ls0));
      GLDS16(Ab + aO1 + ko, (unsigned short*)((char*)&Asm[s3][0] + ls1));
      GLDS16(Bb + bO0 + ko, (unsigned short*)((char*)&Bsm[s3][0] + ls0));
      GLDS16(Bb + bO1 + ko, (unsigned short*)((char*)&Bsm[s3][0] + ls1));
    }
    const char* Ap = (const char*)&Asm[slot][0] + aRd;
    const char* Bp = (const char*)&Bsm[slot][0] + bRd;
    bf16x8 a[4], b[4];
#pragma unroll
    for (int m = 0; m < 4; m++) a[m] = *(const bf16x8*)(Ap + (m << 10));
#pragma unroll
    for (int n = 0; n < 4; n++) b[n] = *(const bf16x8*)(Bp + (n << 10));
    __builtin_amdgcn_s_setprio(1);
#pragma unroll
    for (int m = 0; m < 4; m++)
#pragma unroll
      for (int n = 0; n < 4; n++)
        acc[m][n] = __builtin_amdgcn_mfma_f32_16x16x32_bf16(a[m], b[n], acc[m][n], 0, 0, 0);
    __builtin_amdgcn_s_setprio(0);
    if (kh + 3 < KH) {
      asm volatile("s_waitcnt vmcnt(8)" ::: "memory");
    } else if (kh + 2 < KH) {
      asm volatile("s_waitcnt vmcnt(4)" ::: "memory");
    } else if (kh + 1 < KH) {
      asm volatile("s_waitcnt vmcnt(0)" ::: "memory");
    }
    SBAR();
  }

  const int rcnt = rows - m0;
#pragma unroll
  for (int m = 0; m < 4; m++) {
#pragma unroll
    for (int q = 0; q < 4; q++) {
      int rl = (wr << 6) + (m << 4) + ((lane >> 4) << 2) + q;
      if (rl < rcnt) {
        unsigned short* erow = eout + (size_t)(base + m0 + rl) * D_;
#pragma unroll
        for (int n = 0; n < 4; n++) {
          int ncol = n0 + (wc << 6) + (n << 4) + (lane & 15);
          erow[ncol] = f2bf(acc[m][n][q]);
        }
      }
    }
  }
}

// out[t] = w0*(eout[p0] + b2[e0]) + w1*(eout[p1] + b2[e1])
__global__ void combine_kernel(const unsigned short* __restrict__ eout,
                               const float* __restrict__ b2,
                               const int* __restrict__ sel, const float* __restrict__ wsel,
                               const int* __restrict__ pos,
                               float* __restrict__ out) {
  int t = blockIdx.x;
  int d = threadIdx.x << 2;
  int e0 = sel[t * 2], e1 = sel[t * 2 + 1];
  float w0 = wsel[t * 2], w1 = wsel[t * 2 + 1];
  int p0 = pos[t * 2], p1 = pos[t * 2 + 1];
  ushort4 y0 = *reinterpret_cast<const ushort4*>(eout + (size_t)p0 * D_ + d);
  ushort4 y1 = *reinterpret_cast<const ushort4*>(eout + (size_t)p1 * D_ + d);
  float4 c0 = *reinterpret_cast<const float4*>(b2 + (size_t)e0 * D_ + d);
  float4 c1 = *reinterpret_cast<const float4*>(b2 + (size_t)e1 * D_ + d);
  float4 o;
  o.x = w0 * (bf2f(y0.x) + c0.x) + w1 * (bf2f(y1.x) + c1.x);
  o.y = w0 * (bf2f(y0.y) + c0.y) + w1 * (bf2f(y1.y) + c1.y);
  o.z = w0 * (bf2f(y0.z) + c0.z) + w1 * (bf2f(y1.z) + c1.z);
  o.w = w0 * (bf2f(y0.w) + c0.w) + w1 * (bf2f(y1.w) + c1.w);
  *reinterpret_cast<float4*>(out + (size_t)t * D_ + d) = o;
}

// ---------------- launcher ----------------

extern "C" void kernel_launch(void* const* d_in, const int* in_sizes, int n_in,
                              void* d_out, int out_size, void* d_ws, size_t ws_size,
                              hipStream_t stream) {
  (void)in_sizes; (void)n_in; (void)ws_size; (void)out_size;
  const float* x    = (const float*)d_in[0];
  const float* gate = (const float*)d_in[1];
  const float* W1   = (const float*)d_in[2];
  const float* b1   = (const float*)d_in[3];
  const float* W2   = (const float*)d_in[4];
  const float* b2   = (const float*)d_in[5];
  float* out = (float*)d_out;

  char* p = (char*)d_ws;
  unsigned short* xb   = (unsigned short*)p; p += (size_t)TOKENS * D_ * 2;
  unsigned short* w1t  = (unsigned short*)p; p += (size_t)E_ * H_ * D_ * 2;
  unsigned short* w2t  = (unsigned short*)p; p += (size_t)E_ * D_ * H_ * 2;
  unsigned short* hbuf = (unsigned short*)p; p += (size_t)HPAD_ROWS * H_ * 2;
  int*   tok  = (int*)p;   p += (size_t)RROWS * 4;
  int*   pos  = (int*)p;   p += (size_t)TOKENS * 2 * 4;
  int*   sel  = (int*)p;   p += (size_t)TOKENS * 2 * 4;
  float* wsel = (float*)p; p += (size_t)TOKENS * 2 * 4;
  int* cnt    = (int*)p;   p += 32 * 4;
  int* off    = (int*)p;   p += 32 * 4;
  int* cursor = (int*)p;   p += 32 * 4;
  // eout aliases w1t: w1t (33.55 MB) is dead after gemm1; eout needs RROWS*D_*2
  // = exactly the same size. Rewritten from W1 by transpose_cvt every replay.
  unsigned short* eout = w1t;

  hipMemsetAsync(cnt, 0, 32 * 4, stream);

  transpose_cvt_kernel<<<E_ * (D_ / 64) * (H_ / 64), 256, 0, stream>>>(W1, w1t, D_, H_);
  transpose_cvt_kernel<<<E_ * (H_ / 64) * (D_ / 64), 256, 0, stream>>>(W2, w2t, H_, D_);
  gating_kernel<<<TOKENS / 4, 256, 0, stream>>>(x, gate, xb, sel, wsel, cnt);
  scan_kernel<<<1, 64, 0, stream>>>(cnt, off, cursor);
  scatter_kernel<<<TOKENS / 256, 256, 0, stream>>>(sel, cursor, tok, pos);
  gemm1_kernel<<<E_ * 64 * 16, 256, 0, stream>>>(xb, w1t, b1, hbuf, tok, cnt, off);
  gemm2_kernel<<<E_ * 64 * 8, 256, 0, stream>>>(hbuf, w2t, eout, cnt, off);
  combine_kernel<<<TOKENS, 256, 0, stream>>>(eout, b2, sel, wsel, pos, out);
}

// Round 5
// 371.211 us; speedup vs baseline: 1.7447x; 1.5514x over previous
//
#include <hip/hip_runtime.h>

#define E_      8
#define D_      1024
#define H_      2048
#define TOKENS  8192
#define RROWS   16384            // routed rows total (= TOKENS * TOP_K), exact
#define HPAD_ROWS (RROWS + 128)  // pad so GEMM2 A-staging over-read stays in bounds

using bf16x8 = __attribute__((ext_vector_type(8))) __bf16;
using f32x4  = __attribute__((ext_vector_type(4))) float;

__device__ __forceinline__ unsigned short f2bf(float f) {
  unsigned u = __builtin_bit_cast(unsigned, f);
  u += 0x7fffu + ((u >> 16) & 1u);   // RNE
  return (unsigned short)(u >> 16);
}
__device__ __forceinline__ float bf2f(unsigned short u) {
  unsigned v = (unsigned)u << 16;
  return __builtin_bit_cast(float, v);
}

// async global->LDS, 16B per lane; LDS dest is wave-uniform base + lane*16
#define GLDS16(g, l) __builtin_amdgcn_global_load_lds( \
    (const __attribute__((address_space(1))) unsigned int*)(g), \
    (__attribute__((address_space(3))) unsigned int*)(l), 16, 0, 0)

#define SBAR() asm volatile("s_barrier" ::: "memory")

// ---------------- prologue kernels ----------------

// src: [E][R][C] fp32  ->  dst: [E][C][R] bf16
__global__ void transpose_cvt_kernel(const float* __restrict__ src,
                                     unsigned short* __restrict__ dst,
                                     int R, int C) {
  int tilesC = C >> 6, tilesR = R >> 6;
  int per = tilesR * tilesC;
  int b = blockIdx.x;
  int e = b / per, rem = b % per;
  int rb = rem / tilesC, cb = rem % tilesC;
  __shared__ float tile[64][65];
  const float* s = src + (size_t)e * R * C;
  unsigned short* d = dst + (size_t)e * R * C;
  int r0 = rb << 6, c0 = cb << 6;
#pragma unroll
  for (int i = 0; i < 16; i++) {
    int idx = threadIdx.x + i * 256;
    int lr = idx >> 6, lc = idx & 63;
    tile[lr][lc] = s[(size_t)(r0 + lr) * C + (c0 + lc)];
  }
  __syncthreads();
#pragma unroll
  for (int i = 0; i < 16; i++) {
    int idx = threadIdx.x + i * 256;
    int lr = idx >> 6, lc = idx & 63;
    d[(size_t)(c0 + lr) * R + (r0 + lc)] = f2bf(tile[lc][lr]);
  }
}

// gating + x -> bf16 conversion fused; NO atomics (counts come from route_kernel)
__global__ void gating_kernel(const float* __restrict__ x, const float* __restrict__ gate,
                              unsigned short* __restrict__ xb,
                              int* __restrict__ sel, float* __restrict__ wsel) {
  int lane = threadIdx.x & 63, wid = threadIdx.x >> 6;
  int t = (blockIdx.x << 2) + wid;          // one wave per token
  const float* xr = x + (size_t)t * D_;
  unsigned short* xbr = xb + (size_t)t * D_;
  float acc[8];
#pragma unroll
  for (int e = 0; e < 8; e++) acc[e] = 0.f;
#pragma unroll
  for (int i = 0; i < 4; i++) {
    int d0 = (i << 8) + (lane << 2);
    float4 xv = *reinterpret_cast<const float4*>(xr + d0);
    ushort4 o = make_ushort4(f2bf(xv.x), f2bf(xv.y), f2bf(xv.z), f2bf(xv.w));
    *reinterpret_cast<ushort4*>(xbr + d0) = o;
    float xa[4] = {xv.x, xv.y, xv.z, xv.w};
#pragma unroll
    for (int j = 0; j < 4; j++) {
      const float4* g4 = reinterpret_cast<const float4*>(gate + (size_t)(d0 + j) * 8);
      float4 ga = g4[0], gb = g4[1];
      acc[0] += xa[j] * ga.x; acc[1] += xa[j] * ga.y;
      acc[2] += xa[j] * ga.z; acc[3] += xa[j] * ga.w;
      acc[4] += xa[j] * gb.x; acc[5] += xa[j] * gb.y;
      acc[6] += xa[j] * gb.z; acc[7] += xa[j] * gb.w;
    }
  }
#pragma unroll
  for (int e = 0; e < 8; e++) {
#pragma unroll
    for (int off = 32; off; off >>= 1) acc[e] += __shfl_xor(acc[e], off);
  }
  if (lane == 0) {
    int i0 = 0; float v0 = acc[0];
#pragma unroll
    for (int e = 1; e < 8; e++) if (acc[e] > v0) { v0 = acc[e]; i0 = e; }
    int i1 = -1; float v1 = -3.4e38f;
#pragma unroll
    for (int e = 0; e < 8; e++) if (e != i0 && acc[e] > v1) { v1 = acc[e]; i1 = e; }
    float p1 = expf(v1 - v0);
    float inv = 1.f / (1.f + p1);
    sel[t * 2] = i0; sel[t * 2 + 1] = i1;
    wsel[t * 2] = inv; wsel[t * 2 + 1] = p1 * inv;
  }
}

// Deterministic atomic-free routing: one block, 1024 threads, 16 slots/thread.
// Register histogram -> wave shfl_up scan -> cross-wave scan -> rank assign.
__global__ __launch_bounds__(1024) void route_kernel(
    const int* __restrict__ sel, int* __restrict__ cnt, int* __restrict__ off,
    int* __restrict__ tok_id, int* __restrict__ pos) {
  const int tid = threadIdx.x;
  const int lane = tid & 63, wid = tid >> 6;   // 16 waves
  __shared__ int wtot[16][8];
  __shared__ int woff[16][8];
  __shared__ int offs[8];
  int sv[16];
  const int s0 = tid << 4;
#pragma unroll
  for (int q = 0; q < 4; q++) {
    int4 v = reinterpret_cast<const int4*>(sel + s0)[q];
    sv[q * 4 + 0] = v.x; sv[q * 4 + 1] = v.y;
    sv[q * 4 + 2] = v.z; sv[q * 4 + 3] = v.w;
  }
  int h[8];
#pragma unroll
  for (int e = 0; e < 8; e++) h[e] = 0;
#pragma unroll
  for (int j = 0; j < 16; j++) {
    int ev = sv[j];
#pragma unroll
    for (int e = 0; e < 8; e++) h[e] += (ev == e) ? 1 : 0;
  }
  int excl[8];
#pragma unroll
  for (int e = 0; e < 8; e++) {
    int v = h[e];
#pragma unroll
    for (int d = 1; d < 64; d <<= 1) {
      int u = __shfl_up(v, d);
      if (lane >= d) v += u;
    }
    excl[e] = v - h[e];
    if (lane == 63) wtot[wid][e] = v;
  }
  __syncthreads();
  if (tid == 0) {
    int run[8];
#pragma unroll
    for (int e = 0; e < 8; e++) run[e] = 0;
    for (int w = 0; w < 16; w++)
#pragma unroll
      for (int e = 0; e < 8; e++) { woff[w][e] = run[e]; run[e] += wtot[w][e]; }
    int a = 0;
    for (int e = 0; e < 8; e++) { offs[e] = a; off[e] = a; cnt[e] = run[e]; a += run[e]; }
  }
  __syncthreads();
  int base[8];
#pragma unroll
  for (int e = 0; e < 8; e++) base[e] = offs[e] + woff[wid][e] + excl[e];
#pragma unroll
  for (int j = 0; j < 16; j++) {
    int ev = sv[j];
    int p = 0;
#pragma unroll
    for (int e = 0; e < 8; e++) if (ev == e) { p = base[e]; base[e] = p + 1; }
    pos[s0 + j] = p;
    tok_id[p] = (s0 + j) >> 1;
  }
}

// ---------------- grouped GEMMs ----------------
// 128x128 tile, 4 waves (2x2), 16x16x32 bf16 MFMA, 2 blocks/CU (64KB LDS).
// 4-slot ring of BK=32 K-halves, counted-vmcnt(8) pipeline (T4), prefetch
// distance 3. Swizzle folded into per-lane GLOBAL src (LDS dest linear).
// XCD-chunked block swizzle: expert e's blocks land on XCD e (B panel L2-hot).

__global__ __launch_bounds__(256) void gemm1_kernel(
    const unsigned short* __restrict__ xb,    // [TOKENS][D_] bf16
    const unsigned short* __restrict__ w1t,   // [E][H][D] bf16 (k=d contiguous)
    const float* __restrict__ b1,             // [E][H]
    unsigned short* __restrict__ hbuf,        // [HPAD_ROWS][H_] bf16
    const int* __restrict__ tok_id,
    const int* __restrict__ cnt, const int* __restrict__ off) {
  const int nwg = E_ * 64 * 16;
  const int raw = blockIdx.x;
  const int bid = (raw & 7) * (nwg >> 3) + (raw >> 3);
  const int e  = bid >> 10;
  const int rb = (bid >> 4) & 63;
  const int cb = bid & 15;
  const int rows = cnt[e];
  const int m0 = rb << 7;
  if (m0 >= rows) return;
  const int base = off[e];
  const int tid = threadIdx.x, lane = tid & 63, wid = tid >> 6;
  const int wr = wid >> 1, wc = wid & 1;

  __shared__ __align__(16) unsigned short Asm[4][128 * 32];
  __shared__ __align__(16) unsigned short Bsm[4][128 * 32];

  const int swzc = ((lane >> 2) & 3) ^ (lane >> 4);        // swz(staged row)
  const size_t chk = (size_t)(((lane & 3) ^ swzc) << 4);   // source chunk byte
  const int r0 = wid * 16 + (lane >> 2);                   // 0..63
  const int r1 = r0 + 64;                                  // 64..127
  const int n0 = cb << 7;
  int ar0 = m0 + r0; if (ar0 >= rows) ar0 = rows - 1;      // clamp (never stored)
  int ar1 = m0 + r1; if (ar1 >= rows) ar1 = rows - 1;
  const char* Ab = (const char*)xb;
  const char* Bb = (const char*)w1t + (size_t)e * H_ * D_ * 2;
  const size_t aO0 = (size_t)tok_id[base + ar0] * (D_ * 2) + chk;
  const size_t aO1 = (size_t)tok_id[base + ar1] * (D_ * 2) + chk;
  const size_t bO0 = (size_t)(n0 + r0) * (D_ * 2) + chk;
  const size_t bO1 = (size_t)(n0 + r1) * (D_ * 2) + chk;
  const int ls0 = wid << 10, ls1 = (wid + 4) << 10;        // wave-uniform LDS bases

  const int rchunk = (lane >> 4) ^ (lane & 3) ^ ((lane >> 2) & 3);
  const int aRd = ((wr << 6) + (lane & 15)) * 64 + (rchunk << 4);
  const int bRd = ((wc << 6) + (lane & 15)) * 64 + (rchunk << 4);

  f32x4 acc[4][4] = {};
  const int KH = D_ / 32;   // 32

#pragma unroll
  for (int kh = 0; kh < 3; ++kh) {
    const size_t ko = (size_t)kh << 6;
    GLDS16(Ab + aO0 + ko, (unsigned short*)((char*)&Asm[kh][0] + ls0));
    GLDS16(Ab + aO1 + ko, (unsigned short*)((char*)&Asm[kh][0] + ls1));
    GLDS16(Bb + bO0 + ko, (unsigned short*)((char*)&Bsm[kh][0] + ls0));
    GLDS16(Bb + bO1 + ko, (unsigned short*)((char*)&Bsm[kh][0] + ls1));
  }
  asm volatile("s_waitcnt vmcnt(8)" ::: "memory");   // K-half 0 landed
  SBAR();

#pragma unroll 4
  for (int kh = 0; kh < KH; ++kh) {
    const int slot = kh & 3;
    if (kh + 3 < KH) {
      const int s3 = (kh + 3) & 3;
      const size_t ko = (size_t)(kh + 3) << 6;
      GLDS16(Ab + aO0 + ko, (unsigned short*)((char*)&Asm[s3][0] + ls0));
      GLDS16(Ab + aO1 + ko, (unsigned short*)((char*)&Asm[s3][0] + ls1));
      GLDS16(Bb + bO0 + ko, (unsigned short*)((char*)&Bsm[s3][0] + ls0));
      GLDS16(Bb + bO1 + ko, (unsigned short*)((char*)&Bsm[s3][0] + ls1));
    }
    const char* Ap = (const char*)&Asm[slot][0] + aRd;
    const char* Bp = (const char*)&Bsm[slot][0] + bRd;
    bf16x8 a[4], b[4];
#pragma unroll
    for (int m = 0; m < 4; m++) a[m] = *(const bf16x8*)(Ap + (m << 10));
#pragma unroll
    for (int n = 0; n < 4; n++) b[n] = *(const bf16x8*)(Bp + (n << 10));
    __builtin_amdgcn_s_setprio(1);
#pragma unroll
    for (int m = 0; m < 4; m++)
#pragma unroll
      for (int n = 0; n < 4; n++)
        acc[m][n] = __builtin_amdgcn_mfma_f32_16x16x32_bf16(a[m], b[n], acc[m][n], 0, 0, 0);
    __builtin_amdgcn_s_setprio(0);
    if (kh + 3 < KH) {
      asm volatile("s_waitcnt vmcnt(8)" ::: "memory");   // kh+1 landed
    } else if (kh + 2 < KH) {
      asm volatile("s_waitcnt vmcnt(4)" ::: "memory");
    } else if (kh + 1 < KH) {
      asm volatile("s_waitcnt vmcnt(0)" ::: "memory");
    }
    SBAR();
  }

  const int rcnt = rows - m0;
  const float* b1e = b1 + e * H_;
#pragma unroll
  for (int m = 0; m < 4; m++) {
#pragma unroll
    for (int q = 0; q < 4; q++) {
      int rl = (wr << 6) + (m << 4) + ((lane >> 4) << 2) + q;
      if (rl < rcnt) {
        unsigned short* hrow = hbuf + (size_t)(base + m0 + rl) * H_;
#pragma unroll
        for (int n = 0; n < 4; n++) {
          int ncol = n0 + (wc << 6) + (n << 4) + (lane & 15);
          float v = acc[m][n][q] + b1e[ncol];
          hrow[ncol] = f2bf(fmaxf(v, 0.f));
        }
      }
    }
  }
}

__global__ __launch_bounds__(256) void gemm2_kernel(
    const unsigned short* __restrict__ hbuf,  // [HPAD_ROWS][H_] bf16
    const unsigned short* __restrict__ w2t,   // [E][D][H] bf16 (k=h contiguous)
    unsigned short* __restrict__ eout,        // [RROWS][D_] bf16 (per-slot y)
    const int* __restrict__ cnt, const int* __restrict__ off) {
  const int nwg = E_ * 64 * 8;
  const int raw = blockIdx.x;
  const int bid = (raw & 7) * (nwg >> 3) + (raw >> 3);
  const int e  = bid >> 9;
  const int rb = (bid >> 3) & 63;
  const int cb = bid & 7;
  const int rows = cnt[e];
  const int m0 = rb << 7;
  if (m0 >= rows) return;
  const int base = off[e];
  const int tid = threadIdx.x, lane = tid & 63, wid = tid >> 6;
  const int wr = wid >> 1, wc = wid & 1;

  __shared__ __align__(16) unsigned short Asm[4][128 * 32];
  __shared__ __align__(16) unsigned short Bsm[4][128 * 32];

  const int swzc = ((lane >> 2) & 3) ^ (lane >> 4);
  const size_t chk = (size_t)(((lane & 3) ^ swzc) << 4);
  const int r0 = wid * 16 + (lane >> 2);
  const int r1 = r0 + 64;
  const int n0 = cb << 7;
  const char* Ab = (const char*)hbuf;
  const char* Bb = (const char*)w2t + (size_t)e * D_ * H_ * 2;
  const size_t aO0 = (size_t)(base + m0 + r0) * (H_ * 2) + chk;  // pad-safe overread
  const size_t aO1 = (size_t)(base + m0 + r1) * (H_ * 2) + chk;
  const size_t bO0 = (size_t)(n0 + r0) * (H_ * 2) + chk;
  const size_t bO1 = (size_t)(n0 + r1) * (H_ * 2) + chk;
  const int ls0 = wid << 10, ls1 = (wid + 4) << 10;

  const int rchunk = (lane >> 4) ^ (lane & 3) ^ ((lane >> 2) & 3);
  const int aRd = ((wr << 6) + (lane & 15)) * 64 + (rchunk << 4);
  const int bRd = ((wc << 6) + (lane & 15)) * 64 + (rchunk << 4);

  f32x4 acc[4][4] = {};
  const int KH = H_ / 32;   // 64

#pragma unroll
  for (int kh = 0; kh < 3; ++kh) {
    const size_t ko = (size_t)kh << 6;
    GLDS16(Ab + aO0 + ko, (unsigned short*)((char*)&Asm[kh][0] + ls0));
    GLDS16(Ab + aO1 + ko, (unsigned short*)((char*)&Asm[kh][0] + ls1));
    GLDS16(Bb + bO0 + ko, (unsigned short*)((char*)&Bsm[kh][0] + ls0));
    GLDS16(Bb + bO1 + ko, (unsigned short*)((char*)&Bsm[kh][0] + ls1));
  }
  asm volatile("s_waitcnt vmcnt(8)" ::: "memory");
  SBAR();

#pragma unroll 4
  for (int kh = 0; kh < KH; ++kh) {
    const int slot = kh & 3;
    if (kh + 3 < KH) {
      const int s3 = (kh + 3) & 3;
      const size_t ko = (size_t)(kh + 3) << 6;
      GLDS16(Ab + aO0 + ko, (unsigned short*)((char*)&Asm[s3][0] + ls0));
      GLDS16(Ab + aO1 + ko, (unsigned short*)((char*)&Asm[s3][0] + ls1));
      GLDS16(Bb + bO0 + ko, (unsigned short*)((char*)&Bsm[s3][0] + ls0));
      GLDS16(Bb + bO1 + ko, (unsigned short*)((char*)&Bsm[s3][0] + ls1));
    }
    const char* Ap = (const char*)&Asm[slot][0] + aRd;
    const char* Bp = (const char*)&Bsm[slot][0] + bRd;
    bf16x8 a[4], b[4];
#pragma unroll
    for (int m = 0; m < 4; m++) a[m] = *(const bf16x8*)(Ap + (m << 10));
#pragma unroll
    for (int n = 0; n < 4; n++) b[n] = *(const bf16x8*)(Bp + (n << 10));
    __builtin_amdgcn_s_setprio(1);
#pragma unroll
    for (int m = 0; m < 4; m++)
#pragma unroll
      for (int n = 0; n < 4; n++)
        acc[m][n] = __builtin_amdgcn_mfma_f32_16x16x32_bf16(a[m], b[n], acc[m][n], 0, 0, 0);
    __builtin_amdgcn_s_setprio(0);
    if (kh + 3 < KH) {
      asm volatile("s_waitcnt vmcnt(8)" ::: "memory");
    } else if (kh + 2 < KH) {
      asm volatile("s_waitcnt vmcnt(4)" ::: "memory");
    } else if (kh + 1 < KH) {
      asm volatile("s_waitcnt vmcnt(0)" ::: "memory");
    }
    SBAR();
  }

  const int rcnt = rows - m0;
#pragma unroll
  for (int m = 0; m < 4; m++) {
#pragma unroll
    for (int q = 0; q < 4; q++) {
      int rl = (wr << 6) + (m << 4) + ((lane >> 4) << 2) + q;
      if (rl < rcnt) {
        unsigned short* erow = eout + (size_t)(base + m0 + rl) * D_;
#pragma unroll
        for (int n = 0; n < 4; n++) {
          int ncol = n0 + (wc << 6) + (n << 4) + (lane & 15);
          erow[ncol] = f2bf(acc[m][n][q]);
        }
      }
    }
  }
}

// out[t] = w0*(eout[p0] + b2[e0]) + w1*(eout[p1] + b2[e1])
__global__ void combine_kernel(const unsigned short* __restrict__ eout,
                               const float* __restrict__ b2,
                               const int* __restrict__ sel, const float* __restrict__ wsel,
                               const int* __restrict__ pos,
                               float* __restrict__ out) {
  int t = blockIdx.x;
  int d = threadIdx.x << 2;
  int e0 = sel[t * 2], e1 = sel[t * 2 + 1];
  float w0 = wsel[t * 2], w1 = wsel[t * 2 + 1];
  int p0 = pos[t * 2], p1 = pos[t * 2 + 1];
  ushort4 y0 = *reinterpret_cast<const ushort4*>(eout + (size_t)p0 * D_ + d);
  ushort4 y1 = *reinterpret_cast<const ushort4*>(eout + (size_t)p1 * D_ + d);
  float4 c0 = *reinterpret_cast<const float4*>(b2 + (size_t)e0 * D_ + d);
  float4 c1 = *reinterpret_cast<const float4*>(b2 + (size_t)e1 * D_ + d);
  float4 o;
  o.x = w0 * (bf2f(y0.x) + c0.x) + w1 * (bf2f(y1.x) + c1.x);
  o.y = w0 * (bf2f(y0.y) + c0.y) + w1 * (bf2f(y1.y) + c1.y);
  o.z = w0 * (bf2f(y0.z) + c0.z) + w1 * (bf2f(y1.z) + c1.z);
  o.w = w0 * (bf2f(y0.w) + c0.w) + w1 * (bf2f(y1.w) + c1.w);
  *reinterpret_cast<float4*>(out + (size_t)t * D_ + d) = o;
}

// ---------------- launcher ----------------

extern "C" void kernel_launch(void* const* d_in, const int* in_sizes, int n_in,
                              void* d_out, int out_size, void* d_ws, size_t ws_size,
                              hipStream_t stream) {
  (void)in_sizes; (void)n_in; (void)ws_size; (void)out_size;
  const float* x    = (const float*)d_in[0];
  const float* gate = (const float*)d_in[1];
  const float* W1   = (const float*)d_in[2];
  const float* b1   = (const float*)d_in[3];
  const float* W2   = (const float*)d_in[4];
  const float* b2   = (const float*)d_in[5];
  float* out = (float*)d_out;

  char* p = (char*)d_ws;
  unsigned short* xb   = (unsigned short*)p; p += (size_t)TOKENS * D_ * 2;
  unsigned short* w1t  = (unsigned short*)p; p += (size_t)E_ * H_ * D_ * 2;
  unsigned short* w2t  = (unsigned short*)p; p += (size_t)E_ * D_ * H_ * 2;
  unsigned short* hbuf = (unsigned short*)p; p += (size_t)HPAD_ROWS * H_ * 2;
  int*   tok  = (int*)p;   p += (size_t)RROWS * 4;
  int*   pos  = (int*)p;   p += (size_t)TOKENS * 2 * 4;
  int*   sel  = (int*)p;   p += (size_t)TOKENS * 2 * 4;
  float* wsel = (float*)p; p += (size_t)TOKENS * 2 * 4;
  int* cnt    = (int*)p;   p += 32 * 4;
  int* off    = (int*)p;   p += 32 * 4;
  // eout aliases w1t: w1t (33.55 MB) is dead after gemm1; eout needs RROWS*D_*2
  // = exactly the same size. Rewritten from W1 by transpose_cvt every replay.
  unsigned short* eout = w1t;

  transpose_cvt_kernel<<<E_ * (D_ / 64) * (H_ / 64), 256, 0, stream>>>(W1, w1t, D_, H_);
  transpose_cvt_kernel<<<E_ * (H_ / 64) * (D_ / 64), 256, 0, stream>>>(W2, w2t, H_, D_);
  gating_kernel<<<TOKENS / 4, 256, 0, stream>>>(x, gate, xb, sel, wsel);
  route_kernel<<<1, 1024, 0, stream>>>(sel, cnt, off, tok, pos);
  gemm1_kernel<<<E_ * 64 * 16, 256, 0, stream>>>(xb, w1t, b1, hbuf, tok, cnt, off);
  gemm2_kernel<<<E_ * 64 * 8, 256, 0, stream>>>(hbuf, w2t, eout, cnt, off);
  combine_kernel<<<TOKENS, 256, 0, stream>>>(eout, b2, sel, wsel, pos, out);
}

// Round 6
// 299.067 us; speedup vs baseline: 2.1656x; 1.2412x over previous
//
#include <hip/hip_runtime.h>

#define E_      8
#define D_      1024
#define H_      2048
#define TOKENS  8192
#define RROWS   16384            // routed rows total (= TOKENS * TOP_K), exact
#define HPAD_ROWS (RROWS + 128)  // pad so GEMM2 A-staging over-read stays in bounds

using bf16x8 = __attribute__((ext_vector_type(8))) __bf16;
using f32x4  = __attribute__((ext_vector_type(4))) float;

__device__ __forceinline__ unsigned short f2bf(float f) {
  unsigned u = __builtin_bit_cast(unsigned, f);
  u += 0x7fffu + ((u >> 16) & 1u);   // RNE
  return (unsigned short)(u >> 16);
}
__device__ __forceinline__ float bf2f(unsigned short u) {
  unsigned v = (unsigned)u << 16;
  return __builtin_bit_cast(float, v);
}

// async global->LDS, 16B per lane; LDS dest is wave-uniform base + lane*16
#define GLDS16(g, l) __builtin_amdgcn_global_load_lds( \
    (const __attribute__((address_space(1))) unsigned int*)(g), \
    (__attribute__((address_space(3))) unsigned int*)(l), 16, 0, 0)

#define SBAR() asm volatile("s_barrier" ::: "memory")

// ---------------- prologue kernels ----------------

// src: [E][R][C] fp32  ->  dst: [E][C][R] bf16
__global__ void transpose_cvt_kernel(const float* __restrict__ src,
                                     unsigned short* __restrict__ dst,
                                     int R, int C) {
  int tilesC = C >> 6, tilesR = R >> 6;
  int per = tilesR * tilesC;
  int b = blockIdx.x;
  int e = b / per, rem = b % per;
  int rb = rem / tilesC, cb = rem % tilesC;
  __shared__ float tile[64][65];
  const float* s = src + (size_t)e * R * C;
  unsigned short* d = dst + (size_t)e * R * C;
  int r0 = rb << 6, c0 = cb << 6;
#pragma unroll
  for (int i = 0; i < 16; i++) {
    int idx = threadIdx.x + i * 256;
    int lr = idx >> 6, lc = idx & 63;
    tile[lr][lc] = s[(size_t)(r0 + lr) * C + (c0 + lc)];
  }
  __syncthreads();
#pragma unroll
  for (int i = 0; i < 16; i++) {
    int idx = threadIdx.x + i * 256;
    int lr = idx >> 6, lc = idx & 63;
    d[(size_t)(c0 + lr) * R + (r0 + lc)] = f2bf(tile[lc][lr]);
  }
}

// gating + x -> bf16 conversion fused; NO atomics (counts come from route_kernel)
__global__ void gating_kernel(const float* __restrict__ x, const float* __restrict__ gate,
                              unsigned short* __restrict__ xb,
                              int* __restrict__ sel, float* __restrict__ wsel) {
  int lane = threadIdx.x & 63, wid = threadIdx.x >> 6;
  int t = (blockIdx.x << 2) + wid;          // one wave per token
  const float* xr = x + (size_t)t * D_;
  unsigned short* xbr = xb + (size_t)t * D_;
  float acc[8];
#pragma unroll
  for (int e = 0; e < 8; e++) acc[e] = 0.f;
#pragma unroll
  for (int i = 0; i < 4; i++) {
    int d0 = (i << 8) + (lane << 2);
    float4 xv = *reinterpret_cast<const float4*>(xr + d0);
    ushort4 o = make_ushort4(f2bf(xv.x), f2bf(xv.y), f2bf(xv.z), f2bf(xv.w));
    *reinterpret_cast<ushort4*>(xbr + d0) = o;
    float xa[4] = {xv.x, xv.y, xv.z, xv.w};
#pragma unroll
    for (int j = 0; j < 4; j++) {
      const float4* g4 = reinterpret_cast<const float4*>(gate + (size_t)(d0 + j) * 8);
      float4 ga = g4[0], gb = g4[1];
      acc[0] += xa[j] * ga.x; acc[1] += xa[j] * ga.y;
      acc[2] += xa[j] * ga.z; acc[3] += xa[j] * ga.w;
      acc[4] += xa[j] * gb.x; acc[5] += xa[j] * gb.y;
      acc[6] += xa[j] * gb.z; acc[7] += xa[j] * gb.w;
    }
  }
#pragma unroll
  for (int e = 0; e < 8; e++) {
#pragma unroll
    for (int off = 32; off; off >>= 1) acc[e] += __shfl_xor(acc[e], off);
  }
  if (lane == 0) {
    int i0 = 0; float v0 = acc[0];
#pragma unroll
    for (int e = 1; e < 8; e++) if (acc[e] > v0) { v0 = acc[e]; i0 = e; }
    int i1 = -1; float v1 = -3.4e38f;
#pragma unroll
    for (int e = 0; e < 8; e++) if (e != i0 && acc[e] > v1) { v1 = acc[e]; i1 = e; }
    float p1 = expf(v1 - v0);
    float inv = 1.f / (1.f + p1);
    sel[t * 2] = i0; sel[t * 2 + 1] = i1;
    wsel[t * 2] = inv; wsel[t * 2 + 1] = p1 * inv;
  }
}

// Deterministic atomic-free routing: one block, 1024 threads, 16 slots/thread.
__global__ __launch_bounds__(1024) void route_kernel(
    const int* __restrict__ sel, int* __restrict__ cnt, int* __restrict__ off,
    int* __restrict__ tok_id, int* __restrict__ pos) {
  const int tid = threadIdx.x;
  const int lane = tid & 63, wid = tid >> 6;   // 16 waves
  __shared__ int wtot[16][8];
  __shared__ int woff[16][8];
  __shared__ int offs[8];
  int sv[16];
  const int s0 = tid << 4;
#pragma unroll
  for (int q = 0; q < 4; q++) {
    int4 v = reinterpret_cast<const int4*>(sel + s0)[q];
    sv[q * 4 + 0] = v.x; sv[q * 4 + 1] = v.y;
    sv[q * 4 + 2] = v.z; sv[q * 4 + 3] = v.w;
  }
  int h[8];
#pragma unroll
  for (int e = 0; e < 8; e++) h[e] = 0;
#pragma unroll
  for (int j = 0; j < 16; j++) {
    int ev = sv[j];
#pragma unroll
    for (int e = 0; e < 8; e++) h[e] += (ev == e) ? 1 : 0;
  }
  int excl[8];
#pragma unroll
  for (int e = 0; e < 8; e++) {
    int v = h[e];
#pragma unroll
    for (int d = 1; d < 64; d <<= 1) {
      int u = __shfl_up(v, d);
      if (lane >= d) v += u;
    }
    excl[e] = v - h[e];
    if (lane == 63) wtot[wid][e] = v;
  }
  __syncthreads();
  if (tid == 0) {
    int run[8];
#pragma unroll
    for (int e = 0; e < 8; e++) run[e] = 0;
    for (int w = 0; w < 16; w++)
#pragma unroll
      for (int e = 0; e < 8; e++) { woff[w][e] = run[e]; run[e] += wtot[w][e]; }
    int a = 0;
    for (int e = 0; e < 8; e++) { offs[e] = a; off[e] = a; cnt[e] = run[e]; a += run[e]; }
  }
  __syncthreads();
  int base[8];
#pragma unroll
  for (int e = 0; e < 8; e++) base[e] = offs[e] + woff[wid][e] + excl[e];
#pragma unroll
  for (int j = 0; j < 16; j++) {
    int ev = sv[j];
    int p = 0;
#pragma unroll
    for (int e = 0; e < 8; e++) if (ev == e) { p = base[e]; base[e] = p + 1; }
    pos[s0 + j] = p;
    tok_id[p] = (s0 + j) >> 1;
  }
}

// ---------------- grouped GEMMs ----------------
// 128x128 tile, 4 waves (2x2), BK=64, 2 blocks/CU (64KB LDS).
// LDS: [2 slots][128 rows][128B] bf16, chunk ^= (row&7) swizzle folded into
// the per-lane GLOBAL source address (LDS dest linear) — measured 0 bank
// conflicts (rounds 1-2), vs 8.65M for the 64B-row 4-position swizzle (r5).
// Counted-vmcnt 2-slot schedule (T4): per iter — read 16 frags, lgkmcnt(0)
// + barrier (slot consumable), stage slot kh+2 into the just-read slot,
// 32 MFMA under setprio, vmcnt(8) (stage kh+2 in flight; certifies kh+1
// landed), barrier. XCD-chunked swizzle: expert e -> XCD e (B panel L2-hot).

#define STAGE_T(slot, kh) do { \
  const size_t ko = (size_t)(kh) << 7; \
  _Pragma("unroll") \
  for (int i = 0; i < 4; i++) { \
    GLDS16(Ab + gA[i] + ko, &Asm[slot][((wid << 2) + i) << 9]); \
    GLDS16(Bb + gB[i] + ko, &Bsm[slot][((wid << 2) + i) << 9]); \
  } \
} while (0)

__global__ __launch_bounds__(256, 2) void gemm1_kernel(
    const unsigned short* __restrict__ xb,    // [TOKENS][D_] bf16
    const unsigned short* __restrict__ w1t,   // [E][H][D] bf16 (k=d contiguous)
    const float* __restrict__ b1,             // [E][H]
    unsigned short* __restrict__ hbuf,        // [HPAD_ROWS][H_] bf16
    const int* __restrict__ tok_id,
    const int* __restrict__ cnt, const int* __restrict__ off) {
  const int nwg = E_ * 64 * 16;
  const int raw = blockIdx.x;
  const int bid = (raw & 7) * (nwg >> 3) + (raw >> 3);
  const int e  = bid >> 10;
  const int rb = (bid >> 4) & 63;
  const int cb = bid & 15;
  const int rows = cnt[e];
  const int m0 = rb << 7;
  if (m0 >= rows) return;
  const int base = off[e];
  const int tid = threadIdx.x, lane = tid & 63, wid = tid >> 6;
  const int wr = wid >> 1, wc = wid & 1;

  __shared__ __align__(16) unsigned short Asm[2][128 * 64];
  __shared__ __align__(16) unsigned short Bsm[2][128 * 64];

  // staging: issue i covers rows ((wid*4+i)*8 .. +7); lane: r8 = lane>>3 row,
  // c8 = lane&7 chunk; global chunk = c8 ^ (row&7) = c8 ^ r8.
  const int c8 = lane & 7, r8 = lane >> 3;
  const size_t swz = (size_t)((c8 ^ r8) << 4);
  size_t gA[4], gB[4];
  const int n0 = cb << 7;
#pragma unroll
  for (int i = 0; i < 4; i++) {
    int r = ((wid << 2) + i) << 3;
    int ar = m0 + r + r8; if (ar >= rows) ar = rows - 1;   // clamp (never stored)
    gA[i] = (size_t)tok_id[base + ar] * (D_ * 2) + swz;
    gB[i] = (size_t)(n0 + r + r8) * (D_ * 2) + swz;
  }
  const char* Ab = (const char*)xb;
  const char* Bb = (const char*)w1t + (size_t)e * H_ * D_ * 2;

  // fragment reads: row = w*64 + (lane&15), chunk = ((kk*4 + lane>>4) ^ (row&7))
  const int aRow = ((wr << 6) + (lane & 15)) * 128;
  const int bRow = ((wc << 6) + (lane & 15)) * 128;
  const int cby0 = (((lane >> 4)) ^ (lane & 7)) << 4;
  const int cby1 = ((4 + (lane >> 4)) ^ (lane & 7)) << 4;

  f32x4 acc[4][4] = {};
  const int KH = D_ / 64;   // 16

  STAGE_T(0, 0);
  STAGE_T(1, 1);
  asm volatile("s_waitcnt vmcnt(8)" ::: "memory");   // tile 0 landed
  SBAR();

  for (int kh = 0; kh < KH; ++kh) {
    const int cur = kh & 1;
    const char* Ap = (const char*)&Asm[cur][0] + aRow;
    const char* Bp = (const char*)&Bsm[cur][0] + bRow;
    bf16x8 a[4], b[4], a2[4], b2[4];
#pragma unroll
    for (int m = 0; m < 4; m++) a[m]  = *(const bf16x8*)(Ap + cby0 + m * 2048);
#pragma unroll
    for (int n = 0; n < 4; n++) b[n]  = *(const bf16x8*)(Bp + cby0 + n * 2048);
#pragma unroll
    for (int m = 0; m < 4; m++) a2[m] = *(const bf16x8*)(Ap + cby1 + m * 2048);
#pragma unroll
    for (int n = 0; n < 4; n++) b2[n] = *(const bf16x8*)(Bp + cby1 + n * 2048);
    asm volatile("s_waitcnt lgkmcnt(0)" ::: "memory");
    __builtin_amdgcn_sched_barrier(0);
    SBAR();                                   // all waves done reading slot cur
    if (kh + 2 < KH) STAGE_T(cur, kh + 2);    // overwrite just-consumed slot
    __builtin_amdgcn_s_setprio(1);
#pragma unroll
    for (int m = 0; m < 4; m++)
#pragma unroll
      for (int n = 0; n < 4; n++)
        acc[m][n] = __builtin_amdgcn_mfma_f32_16x16x32_bf16(a[m], b[n], acc[m][n], 0, 0, 0);
#pragma unroll
    for (int m = 0; m < 4; m++)
#pragma unroll
      for (int n = 0; n < 4; n++)
        acc[m][n] = __builtin_amdgcn_mfma_f32_16x16x32_bf16(a2[m], b2[n], acc[m][n], 0, 0, 0);
    __builtin_amdgcn_s_setprio(0);
    if (kh + 2 < KH) {
      asm volatile("s_waitcnt vmcnt(8)" ::: "memory");   // tile kh+1 landed
    } else if (kh + 1 < KH) {
      asm volatile("s_waitcnt vmcnt(0)" ::: "memory");
    }
    SBAR();
  }

  const int rcnt = rows - m0;
  const float* b1e = b1 + e * H_;
#pragma unroll
  for (int m = 0; m < 4; m++) {
#pragma unroll
    for (int q = 0; q < 4; q++) {
      int rl = (wr << 6) + (m << 4) + ((lane >> 4) << 2) + q;
      if (rl < rcnt) {
        unsigned short* hrow = hbuf + (size_t)(base + m0 + rl) * H_;
#pragma unroll
        for (int n = 0; n < 4; n++) {
          int ncol = n0 + (wc << 6) + (n << 4) + (lane & 15);
          float v = acc[m][n][q] + b1e[ncol];
          hrow[ncol] = f2bf(fmaxf(v, 0.f));
        }
      }
    }
  }
}

__global__ __launch_bounds__(256, 2) void gemm2_kernel(
    const unsigned short* __restrict__ hbuf,  // [HPAD_ROWS][H_] bf16
    const unsigned short* __restrict__ w2t,   // [E][D][H] bf16 (k=h contiguous)
    unsigned short* __restrict__ eout,        // [RROWS][D_] bf16 (per-slot y)
    const int* __restrict__ cnt, const int* __restrict__ off) {
  const int nwg = E_ * 64 * 8;
  const int raw = blockIdx.x;
  const int bid = (raw & 7) * (nwg >> 3) + (raw >> 3);
  const int e  = bid >> 9;
  const int rb = (bid >> 3) & 63;
  const int cb = bid & 7;
  const int rows = cnt[e];
  const int m0 = rb << 7;
  if (m0 >= rows) return;
  const int base = off[e];
  const int tid = threadIdx.x, lane = tid & 63, wid = tid >> 6;
  const int wr = wid >> 1, wc = wid & 1;

  __shared__ __align__(16) unsigned short Asm[2][128 * 64];
  __shared__ __align__(16) unsigned short Bsm[2][128 * 64];

  const int c8 = lane & 7, r8 = lane >> 3;
  const size_t swz = (size_t)((c8 ^ r8) << 4);
  size_t gA[4], gB[4];
  const int n0 = cb << 7;
#pragma unroll
  for (int i = 0; i < 4; i++) {
    int r = ((wid << 2) + i) << 3;
    gA[i] = (size_t)(base + m0 + r + r8) * (H_ * 2) + swz;  // pad-safe overread
    gB[i] = (size_t)(n0 + r + r8) * (H_ * 2) + swz;
  }
  const char* Ab = (const char*)hbuf;
  const char* Bb = (const char*)w2t + (size_t)e * D_ * H_ * 2;

  const int aRow = ((wr << 6) + (lane & 15)) * 128;
  const int bRow = ((wc << 6) + (lane & 15)) * 128;
  const int cby0 = (((lane >> 4)) ^ (lane & 7)) << 4;
  const int cby1 = ((4 + (lane >> 4)) ^ (lane & 7)) << 4;

  f32x4 acc[4][4] = {};
  const int KH = H_ / 64;   // 32

  STAGE_T(0, 0);
  STAGE_T(1, 1);
  asm volatile("s_waitcnt vmcnt(8)" ::: "memory");
  SBAR();

  for (int kh = 0; kh < KH; ++kh) {
    const int cur = kh & 1;
    const char* Ap = (const char*)&Asm[cur][0] + aRow;
    const char* Bp = (const char*)&Bsm[cur][0] + bRow;
    bf16x8 a[4], b[4], a2[4], b2[4];
#pragma unroll
    for (int m = 0; m < 4; m++) a[m]  = *(const bf16x8*)(Ap + cby0 + m * 2048);
#pragma unroll
    for (int n = 0; n < 4; n++) b[n]  = *(const bf16x8*)(Bp + cby0 + n * 2048);
#pragma unroll
    for (int m = 0; m < 4; m++) a2[m] = *(const bf16x8*)(Ap + cby1 + m * 2048);
#pragma unroll
    for (int n = 0; n < 4; n++) b2[n] = *(const bf16x8*)(Bp + cby1 + n * 2048);
    asm volatile("s_waitcnt lgkmcnt(0)" ::: "memory");
    __builtin_amdgcn_sched_barrier(0);
    SBAR();
    if (kh + 2 < KH) STAGE_T(cur, kh + 2);
    __builtin_amdgcn_s_setprio(1);
#pragma unroll
    for (int m = 0; m < 4; m++)
#pragma unroll
      for (int n = 0; n < 4; n++)
        acc[m][n] = __builtin_amdgcn_mfma_f32_16x16x32_bf16(a[m], b[n], acc[m][n], 0, 0, 0);
#pragma unroll
    for (int m = 0; m < 4; m++)
#pragma unroll
      for (int n = 0; n < 4; n++)
        acc[m][n] = __builtin_amdgcn_mfma_f32_16x16x32_bf16(a2[m], b2[n], acc[m][n], 0, 0, 0);
    __builtin_amdgcn_s_setprio(0);
    if (kh + 2 < KH) {
      asm volatile("s_waitcnt vmcnt(8)" ::: "memory");
    } else if (kh + 1 < KH) {
      asm volatile("s_waitcnt vmcnt(0)" ::: "memory");
    }
    SBAR();
  }

  const int rcnt = rows - m0;
#pragma unroll
  for (int m = 0; m < 4; m++) {
#pragma unroll
    for (int q = 0; q < 4; q++) {
      int rl = (wr << 6) + (m << 4) + ((lane >> 4) << 2) + q;
      if (rl < rcnt) {
        unsigned short* erow = eout + (size_t)(base + m0 + rl) * D_;
#pragma unroll
        for (int n = 0; n < 4; n++) {
          int ncol = n0 + (wc << 6) + (n << 4) + (lane & 15);
          erow[ncol] = f2bf(acc[m][n][q]);
        }
      }
    }
  }
}

// out[t] = w0*(eout[p0] + b2[e0]) + w1*(eout[p1] + b2[e1])
__global__ void combine_kernel(const unsigned short* __restrict__ eout,
                               const float* __restrict__ b2,
                               const int* __restrict__ sel, const float* __restrict__ wsel,
                               const int* __restrict__ pos,
                               float* __restrict__ out) {
  int t = blockIdx.x;
  int d = threadIdx.x << 2;
  int e0 = sel[t * 2], e1 = sel[t * 2 + 1];
  float w0 = wsel[t * 2], w1 = wsel[t * 2 + 1];
  int p0 = pos[t * 2], p1 = pos[t * 2 + 1];
  ushort4 y0 = *reinterpret_cast<const ushort4*>(eout + (size_t)p0 * D_ + d);
  ushort4 y1 = *reinterpret_cast<const ushort4*>(eout + (size_t)p1 * D_ + d);
  float4 c0 = *reinterpret_cast<const float4*>(b2 + (size_t)e0 * D_ + d);
  float4 c1 = *reinterpret_cast<const float4*>(b2 + (size_t)e1 * D_ + d);
  float4 o;
  o.x = w0 * (bf2f(y0.x) + c0.x) + w1 * (bf2f(y1.x) + c1.x);
  o.y = w0 * (bf2f(y0.y) + c0.y) + w1 * (bf2f(y1.y) + c1.y);
  o.z = w0 * (bf2f(y0.z) + c0.z) + w1 * (bf2f(y1.z) + c1.z);
  o.w = w0 * (bf2f(y0.w) + c0.w) + w1 * (bf2f(y1.w) + c1.w);
  *reinterpret_cast<float4*>(out + (size_t)t * D_ + d) = o;
}

// ---------------- launcher ----------------

extern "C" void kernel_launch(void* const* d_in, const int* in_sizes, int n_in,
                              void* d_out, int out_size, void* d_ws, size_t ws_size,
                              hipStream_t stream) {
  (void)in_sizes; (void)n_in; (void)ws_size; (void)out_size;
  const float* x    = (const float*)d_in[0];
  const float* gate = (const float*)d_in[1];
  const float* W1   = (const float*)d_in[2];
  const float* b1   = (const float*)d_in[3];
  const float* W2   = (const float*)d_in[4];
  const float* b2   = (const float*)d_in[5];
  float* out = (float*)d_out;

  char* p = (char*)d_ws;
  unsigned short* xb   = (unsigned short*)p; p += (size_t)TOKENS * D_ * 2;
  unsigned short* w1t  = (unsigned short*)p; p += (size_t)E_ * H_ * D_ * 2;
  unsigned short* w2t  = (unsigned short*)p; p += (size_t)E_ * D_ * H_ * 2;
  unsigned short* hbuf = (unsigned short*)p; p += (size_t)HPAD_ROWS * H_ * 2;
  int*   tok  = (int*)p;   p += (size_t)RROWS * 4;
  int*   pos  = (int*)p;   p += (size_t)TOKENS * 2 * 4;
  int*   sel  = (int*)p;   p += (size_t)TOKENS * 2 * 4;
  float* wsel = (float*)p; p += (size_t)TOKENS * 2 * 4;
  int* cnt    = (int*)p;   p += 32 * 4;
  int* off    = (int*)p;   p += 32 * 4;
  // eout aliases w1t: w1t (33.55 MB) is dead after gemm1; eout needs RROWS*D_*2
  // = exactly the same size. Rewritten from W1 by transpose_cvt every replay.
  unsigned short* eout = w1t;

  transpose_cvt_kernel<<<E_ * (D_ / 64) * (H_ / 64), 256, 0, stream>>>(W1, w1t, D_, H_);
  transpose_cvt_kernel<<<E_ * (H_ / 64) * (D_ / 64), 256, 0, stream>>>(W2, w2t, H_, D_);
  gating_kernel<<<TOKENS / 4, 256, 0, stream>>>(x, gate, xb, sel, wsel);
  route_kernel<<<1, 1024, 0, stream>>>(sel, cnt, off, tok, pos);
  gemm1_kernel<<<E_ * 64 * 16, 256, 0, stream>>>(xb, w1t, b1, hbuf, tok, cnt, off);
  gemm2_kernel<<<E_ * 64 * 8, 256, 0, stream>>>(hbuf, w2t, eout, cnt, off);
  combine_kernel<<<TOKENS, 256, 0, stream>>>(eout, b2, sel, wsel, pos, out);
}